// Round 4
// baseline (271.407 us; speedup 1.0000x reference)
//
#include <hip/hip_runtime.h>
#include <hip/hip_fp16.h>
#include <stdint.h>
#include <string.h>

// LightGCN propagation — R18: drop the bucket sort; build ELL directly in
// global memory with per-row atomics (mean degree 8 over 150K counters =>
// negligible contention). Removes k1's 66KB LDS staging (was 1 block/CU,
// 261K bank conflicts) and s1's barr round-trip + LDS ELL build.
//  K1': edge scatter -> global ELL via atomicAdd(counts[row]) + mark + cvt.
//  l1:  layer-1 spmm from global ELL over ALL rows (no LDS, 256-thr) +
//       acc0 + mask-expand + mask-copy ride-alongs.
//  spmm2: layer-2 spmm (mask2 rows) + acc1 ride-along.
//  sp3dot: slot-form layer 3 + fused batched dot (paired 16-lane groups).

#define NUM_USERS 100000
#define NUM_ITEMS 50000
#define N_NODES   150000
#define DIM       64
#define N_EDGES   1200000
#define ND        (N_NODES * DIM)
#define NB        4096
#define NSAMP     (2 * NB)

#define ELL_W     24                // P(Poisson(8) > 24) ~ 4e-7 -> ovf backstop
#define NROWS_PAD 150016            // 9376 * 16
#define OVF_CAP   512

#define E_BLOCKS    1172            // 1172*256*4 = 1,200,128 >= N_EDGES
#define MARK_BLOCKS 32              // 32*256 = 8192 = NSAMP
#define CVT_BLOCKS  1172

#define L1_ROW_BLOCKS 9376          // 16 rows/block -> 150016 rows (guarded)
#define L1_ACC_BLOCKS 512           // 16 slots/block -> 8192
#define L1_EXP_BLOCKS 1024
#define L1_CPY_BLOCKS 256           // grid-stride over N_NODES

#define SPMM_BLOCKS   9375          // 16 rows/block = 150000 exactly
#define ACC_BLOCKS    512
#define SP3_BLOCKS    512           // 16 groups/block over 8192 slot-groups

// ---- fp16 pack/unpack helpers (compute in fp32) ---------------------------
__device__ __forceinline__ int h2i(__half2 h) { int r; memcpy(&r, &h, 4); return r; }
__device__ __forceinline__ __half2 i2h(int i) { __half2 h; memcpy(&h, &i, 4); return h; }

__device__ __forceinline__ float4 loadh4(const __half* p) {
    int2 v = *(const int2*)p;
    float2 a = __half22float2(i2h(v.x));
    float2 b = __half22float2(i2h(v.y));
    return make_float4(a.x, a.y, b.x, b.y);
}
__device__ __forceinline__ void storeh4(__half* p, float4 v) {
    int2 o;
    o.x = h2i(__floats2half2_rn(v.x, v.y));
    o.y = h2i(__floats2half2_rn(v.z, v.w));
    *(int2*)p = o;
}
__device__ __forceinline__ float4 f4fma(float v, float4 x, float4 a) {
    a.x += v * x.x; a.y += v * x.y; a.z += v * x.z; a.w += v * x.w;
    return a;
}

// weighted neighbor sum for one row (16-lane group, lane-subrange t) --------
__device__ __forceinline__ float4 ell_sum(const int2* __restrict__ ep, int cnt,
                                          const __half* __restrict__ xsrc, int t,
                                          const int4* __restrict__ ovf, int novf,
                                          int row) {
    float4 a0 = {0,0,0,0}, a1 = {0,0,0,0}, a2 = {0,0,0,0}, a3 = {0,0,0,0};
    int j = 0;
    for (; j + 4 <= cnt; j += 4) {
        int4 cv0 = *(const int4*)(ep + j);
        int4 cv1 = *(const int4*)(ep + j + 2);
        float4 x0 = loadh4(xsrc + (size_t)cv0.x * DIM + t * 4);
        float4 x1 = loadh4(xsrc + (size_t)cv0.z * DIM + t * 4);
        float4 x2 = loadh4(xsrc + (size_t)cv1.x * DIM + t * 4);
        float4 x3 = loadh4(xsrc + (size_t)cv1.z * DIM + t * 4);
        a0 = f4fma(__int_as_float(cv0.y), x0, a0);
        a1 = f4fma(__int_as_float(cv0.w), x1, a1);
        a2 = f4fma(__int_as_float(cv1.y), x2, a2);
        a3 = f4fma(__int_as_float(cv1.w), x3, a3);
    }
    for (; j + 2 <= cnt; j += 2) {
        int4 cv = *(const int4*)(ep + j);
        float4 x0 = loadh4(xsrc + (size_t)cv.x * DIM + t * 4);
        float4 x1 = loadh4(xsrc + (size_t)cv.z * DIM + t * 4);
        a0 = f4fma(__int_as_float(cv.y), x0, a0);
        a1 = f4fma(__int_as_float(cv.w), x1, a1);
    }
    if (j < cnt) {
        int2 cv = ep[j];
        float4 xv = loadh4(xsrc + (size_t)cv.x * DIM + t * 4);
        a0 = f4fma(__int_as_float(cv.y), xv, a0);
    }
    for (int k = 0; k < novf; ++k) {
        int4 o = ovf[k];
        if (o.x == row) {
            float4 xv = loadh4(xsrc + (size_t)o.y * DIM + t * 4);
            a0 = f4fma(__int_as_float(o.z), xv, a0);
        }
    }
    float4 r;
    r.x = (a0.x + a1.x) + (a2.x + a3.x);
    r.y = (a0.y + a1.y) + (a2.y + a3.y);
    r.z = (a0.z + a1.z) + (a2.z + a3.z);
    r.w = (a0.w + a1.w) + (a2.w + a3.w);
    return r;
}

// ---------------------------------------------------------------------------
// K1': direct global ELL scatter + mark + cvt
// ---------------------------------------------------------------------------
__global__ __launch_bounds__(256)
void k1_kernel(const int* __restrict__ erow,
               const int* __restrict__ ecol,
               const float* __restrict__ evalv,
               const int* __restrict__ users,
               const int* __restrict__ items,
               const float* __restrict__ ue,
               const float* __restrict__ ie,
               int* __restrict__ counts,
               int2* __restrict__ ell,
               int4* __restrict__ ovf,
               int* __restrict__ ovf_cnt,
               unsigned char* __restrict__ mask3,
               __half* __restrict__ xh) {
    const int bid = blockIdx.x;
    if (bid < E_BLOCKS) {
        int base = (bid * 256 + (int)threadIdx.x) * 4;
        if (base < N_EDGES) {            // N_EDGES % 4 == 0 -> all 4 valid
            int4   r4 = *(const int4*)(erow + base);
            int4   c4 = *(const int4*)(ecol + base);
            float4 v4 = *(const float4*)(evalv + base);
            int   rr[4] = {r4.x, r4.y, r4.z, r4.w};
            int   cc[4] = {c4.x, c4.y, c4.z, c4.w};
            float vv[4] = {v4.x, v4.y, v4.z, v4.w};
            #pragma unroll
            for (int u = 0; u < 4; ++u) {
                int slot = atomicAdd(&counts[rr[u]], 1);
                if (slot < ELL_W) {
                    ell[(size_t)rr[u] * ELL_W + slot] =
                        make_int2(cc[u], __float_as_int(vv[u]));
                } else {
                    int q = atomicAdd(ovf_cnt, 1);
                    if (q < OVF_CAP)
                        ovf[q] = make_int4(rr[u], cc[u], __float_as_int(vv[u]), 0);
                }
            }
        }
    } else if (bid < E_BLOCKS + MARK_BLOCKS) {
        int i = (bid - E_BLOCKS) * 256 + (int)threadIdx.x;
        if (i < NB)         mask3[users[i]] = 1;
        else if (i < NSAMP) mask3[NUM_USERS + items[i - NB]] = 1;
    } else {
        const int n4  = ND / 4;
        const int nu4 = NUM_USERS * DIM / 4;
        int i = (bid - E_BLOCKS - MARK_BLOCKS) * 256 + (int)threadIdx.x;
        const int stride = CVT_BLOCKS * 256;
        int2* xh4 = (int2*)xh;
        for (; i < n4; i += stride) {
            float4 v = (i < nu4) ? ((const float4*)ue)[i]
                                 : ((const float4*)ie)[i - nu4];
            int2 o;
            o.x = h2i(__floats2half2_rn(v.x, v.y));
            o.y = h2i(__floats2half2_rn(v.z, v.w));
            xh4[i] = o;
        }
    }
}

// ---------------------------------------------------------------------------
// l1: layer-1 spmm over ALL rows from global ELL (no LDS)
//     + acc0 + mask expand + mask copy ride-alongs
// ---------------------------------------------------------------------------
__global__ __launch_bounds__(256)
void l1_kernel(const int* __restrict__ erow,
               const int* __restrict__ ecol,
               const int* __restrict__ counts,
               const int2* __restrict__ ell,
               const __half* __restrict__ xh,
               const float* __restrict__ ue,
               const float* __restrict__ ie,
               const int4* __restrict__ ovf,
               const int* __restrict__ ovf_cnt,
               const unsigned char* __restrict__ mask3,
               unsigned char* __restrict__ mask2,
               const int* __restrict__ users,
               const int* __restrict__ items,
               float* __restrict__ acc_small,
               __half* __restrict__ emb_out) {
    const int bid  = blockIdx.x;
    const int wid  = threadIdx.x >> 6;
    const int lane = threadIdx.x & 63;
    const int g    = lane >> 4;
    const int t    = lane & 15;

    if (bid < L1_ROW_BLOCKS) {
        const int row = bid * 16 + wid * 4 + g;
        const bool active = row < N_NODES;
        int cnt = 0;
        if (active) {
            cnt = counts[row];
            cnt = cnt < ELL_W ? cnt : ELL_W;
        }
        int novf = *ovf_cnt;
        novf = novf < OVF_CAP ? novf : OVF_CAP;
        float4 s = ell_sum(ell + (size_t)row * ELL_W, cnt, xh, t, ovf, novf, row);
        if (active) {
            float4 self = loadh4(xh + (size_t)row * DIM + t * 4);
            float4 r;
            r.x = 0.2f * self.x + 0.8f * s.x;
            r.y = 0.2f * self.y + 0.8f * s.y;
            r.z = 0.2f * self.z + 0.8f * s.z;
            r.w = 0.2f * self.w + 0.8f * s.w;
            storeh4(emb_out + (size_t)row * DIM + t * 4, r);
        }
    } else if (bid < L1_ROW_BLOCKS + L1_ACC_BLOCKS) {
        // acc0: layer-0 contribution from the fp32 tables (16 slots/block)
        const int s = (bid - L1_ROW_BLOCKS) * 16 + wid * 4 + g;   // < 8192
        const int node = (s < NB) ? users[s] : (NUM_USERS + items[s - NB]);
        const float* p = (node < NUM_USERS) ? ue + (size_t)node * DIM
                                            : ie + (size_t)(node - NUM_USERS) * DIM;
        *(float4*)(acc_small + (size_t)s * DIM + t * 4) = *(const float4*)(p + t * 4);
    } else if (bid < L1_ROW_BLOCKS + L1_ACC_BLOCKS + L1_EXP_BLOCKS) {
        int i = (bid - L1_ROW_BLOCKS - L1_ACC_BLOCKS) * 256 + (int)threadIdx.x;
        const int stride = L1_EXP_BLOCKS * 256;
        for (; i < N_EDGES; i += stride)
            if (mask3[erow[i]]) mask2[ecol[i]] = 1;
    } else {
        int i = (bid - L1_ROW_BLOCKS - L1_ACC_BLOCKS - L1_EXP_BLOCKS) * 256
                + (int)threadIdx.x;
        const int stride = L1_CPY_BLOCKS * 256;
        for (; i < N_NODES; i += stride)
            if (mask3[i]) mask2[i] = 1;
    }
}

// ---------------------------------------------------------------------------
// spmm2 (layer 2): global ELL, masked, fp16 gathers + acc1 ride-along
// ---------------------------------------------------------------------------
__global__ __launch_bounds__(256)
void spmm_kernel(const int* __restrict__ counts,
                 const int2* __restrict__ ell,
                 const __half* __restrict__ xsrc,
                 const unsigned char* __restrict__ mask,
                 const int* __restrict__ ovf_cnt,
                 const int4* __restrict__ ovf,
                 const int* __restrict__ users,
                 const int* __restrict__ items,
                 float* __restrict__ acc_small,
                 __half* __restrict__ xout) {
    const int wid  = threadIdx.x >> 6;
    const int lane = threadIdx.x & 63;
    const int g    = lane >> 4;
    const int t    = lane & 15;

    if (blockIdx.x < SPMM_BLOCKS) {
        const int row = blockIdx.x * 16 + wid * 4 + g;   // < 150000
        bool active = mask[row] != 0;
        int cnt = 0;
        if (active) {
            cnt = counts[row];
            cnt = cnt < ELL_W ? cnt : ELL_W;
        }
        int novf = *ovf_cnt;
        novf = novf < OVF_CAP ? novf : OVF_CAP;
        float4 s = ell_sum(ell + (size_t)row * ELL_W, cnt, xsrc, t, ovf,
                           active ? novf : 0, row);
        if (active) {
            float4 self = loadh4(xsrc + (size_t)row * DIM + t * 4);
            float4 r;
            r.x = 0.2f * self.x + 0.8f * s.x;
            r.y = 0.2f * self.y + 0.8f * s.y;
            r.z = 0.2f * self.z + 0.8f * s.z;
            r.w = 0.2f * self.w + 0.8f * s.w;
            storeh4(xout + (size_t)row * DIM + t * 4, r);
        }
    } else {
        // acc1 += e1 at sampled slots (xsrc = emb_a)
        const int s = (blockIdx.x - SPMM_BLOCKS) * 16 + wid * 4 + g;
        const int node = (s < NB) ? users[s] : (NUM_USERS + items[s - NB]);
        float4 v = loadh4(xsrc + (size_t)node * DIM + t * 4);
        float4* ap = (float4*)(acc_small + (size_t)s * DIM + t * 4);
        float4 a = *ap;
        a.x += v.x; a.y += v.y; a.z += v.z; a.w += v.w;
        *ap = a;
    }
}

// ---------------------------------------------------------------------------
// sp3dot: slot-form layer 3 + fused batched dot.
//   Pair (user slot w, item slot NB+w) sit in adjacent 16-lane groups of the
//   same wave -> partner acc via shfl_xor(16), reduce via shfl_xor(1,2,4,8).
// ---------------------------------------------------------------------------
__global__ __launch_bounds__(256)
void sp3dot_kernel(const int* __restrict__ counts,
                   const int2* __restrict__ ell,
                   const __half* __restrict__ emb2,
                   const int* __restrict__ ovf_cnt,
                   const int4* __restrict__ ovf,
                   const int* __restrict__ users,
                   const int* __restrict__ items,
                   const float* __restrict__ acc_small,
                   float* __restrict__ out) {
    const int wid  = threadIdx.x >> 6;
    const int lane = threadIdx.x & 63;
    const int g    = lane >> 4;
    const int t    = lane & 15;
    const int G    = blockIdx.x * 16 + wid * 4 + g;       // < 8192
    if (G >= NSAMP) return;
    const int w    = G >> 1;
    const int role = G & 1;                    // 0 = user slot, 1 = item slot
    const int s    = role ? (NB + w) : w;
    const int node = role ? (NUM_USERS + items[w]) : users[w];

    int cnt = counts[node];
    cnt = cnt < ELL_W ? cnt : ELL_W;
    int novf = *ovf_cnt;
    novf = novf < OVF_CAP ? novf : OVF_CAP;
    float4 sm = ell_sum(ell + (size_t)node * ELL_W, cnt, emb2, t, ovf, novf, node);
    float4 self = loadh4(emb2 + (size_t)node * DIM + t * 4);
    float4 a = *(const float4*)(acc_small + (size_t)s * DIM + t * 4);  // e0+e1
    a.x += 1.2f * self.x + 0.8f * sm.x;
    a.y += 1.2f * self.y + 0.8f * sm.y;
    a.z += 1.2f * self.z + 0.8f * sm.z;
    a.w += 1.2f * self.w + 0.8f * sm.w;
    // fused dot: partner group is lane^16 within the same wave
    float4 b;
    b.x = __shfl_xor(a.x, 16, 64);
    b.y = __shfl_xor(a.y, 16, 64);
    b.z = __shfl_xor(a.z, 16, 64);
    b.w = __shfl_xor(a.w, 16, 64);
    float p = a.x * b.x + a.y * b.y + a.z * b.z + a.w * b.w;
    p += __shfl_xor(p, 1, 64);
    p += __shfl_xor(p, 2, 64);
    p += __shfl_xor(p, 4, 64);
    p += __shfl_xor(p, 8, 64);
    if (role == 0 && t == 0) out[w] = p * 0.0625f;   // (u/4)·(i/4)
}

// ---------------------------------------------------------------------------
extern "C" void kernel_launch(void* const* d_in, const int* in_sizes, int n_in,
                              void* d_out, int out_size, void* d_ws, size_t ws_size,
                              hipStream_t stream) {
    const int*   users = (const int*)  d_in[0];
    const int*   items = (const int*)  d_in[1];
    const int*   erow  = (const int*)  d_in[2];
    const int*   ecol  = (const int*)  d_in[3];
    const float* evalv = (const float*)d_in[4];
    const float* ue    = (const float*)d_in[5];
    const float* ie    = (const float*)d_in[6];
    float* out = (float*)d_out;

    // workspace layout (~89.4 MB)
    __half* xh        = (__half*)d_ws;                      // 19.2 MB
    __half* emb_a     = xh + ND;                            // 19.2 MB
    __half* emb_b     = emb_a + ND;                         // 19.2 MB
    float*  acc_small = (float*)(emb_b + ND);               // 2.1 MB
    int2*   ell       = (int2*)(acc_small + NSAMP * DIM);   // 28.8 MB
    int*    counts    = (int*)(ell + (size_t)NROWS_PAD * ELL_W); // 600 KB
    int*    ovf_cnt   = counts + NROWS_PAD;                 // 1
    int4*   ovf       = (int4*)(((uintptr_t)(ovf_cnt + 1) + 15) & ~(uintptr_t)15);
    unsigned char* mask3 = (unsigned char*)(ovf + OVF_CAP); // N_NODES
    unsigned char* mask2 = mask3 + N_NODES;                 // N_NODES

    // zero counts | ovf_cnt | ovf | mask3 | mask2 (contiguous, ~908 KB)
    size_t zbytes = (size_t)((mask2 + N_NODES) - (unsigned char*)counts);
    hipMemsetAsync(counts, 0, zbytes, stream);

    // k1': edge scatter to global ELL + mark + cvt
    k1_kernel<<<E_BLOCKS + MARK_BLOCKS + CVT_BLOCKS, 256, 0, stream>>>(
        erow, ecol, evalv, users, items, ue, ie,
        counts, ell, ovf, ovf_cnt, mask3, xh);

    // l1: layer-1 spmm (all rows) + acc0 + expand + copy
    l1_kernel<<<L1_ROW_BLOCKS + L1_ACC_BLOCKS + L1_EXP_BLOCKS + L1_CPY_BLOCKS, 256, 0, stream>>>(
        erow, ecol, counts, ell, xh, ue, ie, ovf, ovf_cnt,
        mask3, mask2, users, items, acc_small, emb_a);

    // layer 2 (mask2) + acc1 (from emb_a)
    spmm_kernel<<<SPMM_BLOCKS + ACC_BLOCKS, 256, 0, stream>>>(
        counts, ell, emb_a, mask2, ovf_cnt, ovf,
        users, items, acc_small, emb_b);

    // layer 3 slot-form + fused dot
    sp3dot_kernel<<<SP3_BLOCKS, 256, 0, stream>>>(
        counts, ell, emb_b, ovf_cnt, ovf, users, items, acc_small, out);
}